// Round 4
// baseline (375.465 us; speedup 1.0000x reference)
//
#include <hip/hip_runtime.h>
#include <cmath>

#define B_ 32
#define N_ 4096
#define IN_DIM 125
#define ADIM 128
#define KDIM 64
#define DMODEL 1024
#define HID 64
#define KEFF 256
#define EPS_ 1e-6f

// ---------- k1: saliency MLP in fp64 (r1 structure, f32 weights inline) ----
// r0-r3 verdict: the s_load W path stalls at ~52% VALU regardless of
// occupancy/traffic; LDS-broadcast W (r2) and VMEM W (r3) are worse.
// Keep the winner. Weights now read as f32 (cvt_f64_f32 is exact ->
// bit-identical salD) which eliminates the k0 conversion kernel+launch.
// 128 pts/block, 512 thr (8 waves); wave w owns j-octet, lane owns 2 pts.
#define K1_PTS 128
__global__ __launch_bounds__(512) void k1_saliency(
    const float* __restrict__ x, const float* __restrict__ W1,
    const float* __restrict__ b1, const float* __restrict__ W2,
    const float* __restrict__ b2, double* __restrict__ salD,
    float* __restrict__ salF)
{
  __shared__ double smem[8000];              // 64000 B (xs + red overlay)
  float* xs = (float*)smem;                  // [128][125]
  int tid = threadIdx.x;
  int p0 = blockIdx.x * K1_PTS;

  { // stage x tile: 16000 floats = 4000 float4 (byte base 64000*bid, 16B ok)
    const float4* src = (const float4*)(x + (size_t)p0 * IN_DIM);
    float4* dst = (float4*)xs;
    for (int e = tid; e < (K1_PTS * IN_DIM) / 4; e += 512) dst[e] = src[e];
  }
  __syncthreads();

  int wv = __builtin_amdgcn_readfirstlane(tid >> 6);
  int lane = tid & 63;
  int jb = wv * 8;

  double acc0[8], acc1[8];
  #pragma unroll
  for (int jj = 0; jj < 8; ++jj) {
    double bv = (double)b1[jb + jj];
    acc0[jj] = bv; acc1[jj] = bv;
  }

  const float* xr0 = xs + lane * IN_DIM;          // stride 125 dw: 2-way free
  const float* xr1 = xs + (64 + lane) * IN_DIM;
  float wA[8], wB[8];
  #pragma unroll
  for (int jj = 0; jj < 8; ++jj) wA[jj] = W1[jb + jj];     // row 0
  float xv0 = xr0[0];
  float yv0 = xr1[0];

  #pragma unroll 1
  for (int d = 0; d < 124; d += 2) {
    float xv1 = xr0[d + 1];
    float yv1 = xr1[d + 1];
    #pragma unroll
    for (int jj = 0; jj < 8; ++jj) wB[jj] = W1[(d + 1) * HID + jb + jj];
    double xd0 = (double)xv0, yd0 = (double)yv0;
    #pragma unroll
    for (int jj = 0; jj < 8; ++jj) acc0[jj] = fma(xd0, (double)wA[jj], acc0[jj]);
    #pragma unroll
    for (int jj = 0; jj < 8; ++jj) acc1[jj] = fma(yd0, (double)wA[jj], acc1[jj]);
    xv0 = xr0[d + 2];
    yv0 = xr1[d + 2];
    #pragma unroll
    for (int jj = 0; jj < 8; ++jj) wA[jj] = W1[(d + 2) * HID + jb + jj];
    double xd1 = (double)xv1, yd1 = (double)yv1;
    #pragma unroll
    for (int jj = 0; jj < 8; ++jj) acc0[jj] = fma(xd1, (double)wB[jj], acc0[jj]);
    #pragma unroll
    for (int jj = 0; jj < 8; ++jj) acc1[jj] = fma(yd1, (double)wB[jj], acc1[jj]);
  }
  { // d = 124 (wA holds row 124)
    double xd = (double)xv0, yd = (double)yv0;
    #pragma unroll
    for (int jj = 0; jj < 8; ++jj) {
      acc0[jj] = fma(xd, (double)wA[jj], acc0[jj]);
      acc1[jj] = fma(yd, (double)wA[jj], acc1[jj]);
    }
  }

  double part0 = 0.0, part1 = 0.0;
  #pragma unroll
  for (int jj = 0; jj < 8; ++jj) {
    double w2 = (double)W2[jb + jj];
    part0 = fma(fmax(acc0[jj], 0.0), w2, part0);
    part1 = fma(fmax(acc1[jj], 0.0), w2, part1);
  }
  __syncthreads();                           // xs reads done
  double* red = smem;                        // [8][128] overlay (8 KB)
  red[wv * K1_PTS + lane] = part0;
  red[wv * K1_PTS + 64 + lane] = part1;
  __syncthreads();
  if (tid < K1_PTS) {
    double s = (double)b2[0];
    #pragma unroll
    for (int w = 0; w < 8; ++w) s += red[w * K1_PTS + tid];
    double sg = 1.0 / (1.0 + exp(-s));
    salD[p0 + tid] = sg;                     // f64 sort key (monotone == y*)
    salF[p0 + tid] = (float)sg;
  }
}

// ---- kA: fused {k3a chunk-sort (blocks 0..255)} + {k2 softmax/cumsum
//      (blocks 256..287)}. Both depend only on k1; one launch. ----
__global__ __launch_bounds__(256) void kA_softmax_sort(
    const double* __restrict__ salD, const float* __restrict__ salF,
    float* __restrict__ ystar, float* __restrict__ csal,
    unsigned long long* __restrict__ candK, int* __restrict__ candI)
{
  __shared__ unsigned long long K[512];     // k3a path (4 KB)
  __shared__ int I[512];                    // (2 KB)
  __shared__ float wmax[4], wsum[4], wtot[4];
  int t = threadIdx.x;

  if (blockIdx.x < 256) {
    // ---------------- k3a: sort 512-chunk desc, keep top-256 ------------
    int bid = blockIdx.x;
    int b = bid >> 3, c = bid & 7;
    const double* y = salD + (size_t)b * N_ + c * 512;
    for (int i = t; i < 512; i += 256) {
      K[i] = __double_as_longlong(y[i]);    // y in (0,1): bits monotone
      I[i] = c * 512 + i;
    }
    __syncthreads();
    for (int k = 2; k <= 512; k <<= 1) {
      for (int j = k >> 1; j > 0; j >>= 1) {
        for (int i = t; i < 512; i += 256) {
          int l = i ^ j;
          if (l > i) {
            unsigned long long a = K[i], cc = K[l];
            int ai = I[i], ci = I[l];
            bool prec = (a > cc) || (a == cc && ai < ci);
            bool up = ((i & k) == 0);
            if (up ? !prec : prec) { K[i] = cc; K[l] = a; I[i] = ci; I[l] = ai; }
          }
        }
        __syncthreads();
      }
    }
    if (t < 256) {
      candK[(b * 8 + c) * 256 + t] = K[t];
      candI[(b * 8 + c) * 256 + t] = I[t];
    }
  } else {
    // ---------------- k2: softmax(sal/0.5) + cumsum(sal)/N --------------
    int b = blockIdx.x - 256;
    int lane = t & 63, wv = t >> 6;
    const float4* s4 = (const float4*)(salF + (size_t)b * N_);
    float v[16];
    #pragma unroll
    for (int k = 0; k < 4; ++k) {
      float4 a = s4[t * 4 + k];
      v[4*k] = a.x; v[4*k+1] = a.y; v[4*k+2] = a.z; v[4*k+3] = a.w;
    }
    float m = v[0];
    #pragma unroll
    for (int i = 1; i < 16; ++i) m = fmaxf(m, v[i]);
    #pragma unroll
    for (int off = 32; off > 0; off >>= 1) m = fmaxf(m, __shfl_down(m, off));
    if (lane == 0) wmax[wv] = m;
    __syncthreads();
    float M = fmaxf(fmaxf(wmax[0], wmax[1]), fmaxf(wmax[2], wmax[3]));

    float e[16];
    float se = 0.f;
    #pragma unroll
    for (int i = 0; i < 16; ++i) { e[i] = expf((v[i] - M) * 2.0f); se += e[i]; }
    float ss = se;
    #pragma unroll
    for (int off = 32; off > 0; off >>= 1) ss += __shfl_down(ss, off);
    if (lane == 0) wsum[wv] = ss;
    __syncthreads();
    float denom = (wsum[0] + wsum[1]) + (wsum[2] + wsum[3]);
    float rdenom = 1.f / denom;

    float p[16];
    p[0] = v[0];
    #pragma unroll
    for (int i = 1; i < 16; ++i) p[i] = p[i-1] + v[i];
    float T = p[15];
    float incl = T;
    #pragma unroll
    for (int off = 1; off < 64; off <<= 1) {
      float nv = __shfl_up(incl, off);
      if (lane >= off) incl += nv;
    }
    float wexcl = incl - T;
    if (lane == 63) wtot[wv] = incl;
    __syncthreads();
    float woff = 0.f;
    for (int w = 0; w < 4; ++w) if (w < wv) woff += wtot[w];
    float base = woff + wexcl;

    float4* y4 = (float4*)(ystar + (size_t)b * N_);
    float4* c4 = (float4*)(csal + (size_t)b * N_);
    const float invN = 1.f / (float)N_;
    #pragma unroll
    for (int k = 0; k < 4; ++k) {
      float4 yo, co;
      yo.x = e[4*k]   * rdenom; co.x = (base + p[4*k])   * invN;
      yo.y = e[4*k+1] * rdenom; co.y = (base + p[4*k+1]) * invN;
      yo.z = e[4*k+2] * rdenom; co.z = (base + p[4*k+2]) * invN;
      yo.w = e[4*k+3] * rdenom; co.w = (base + p[4*k+3]) * invN;
      y4[t * 4 + k] = yo;
      c4[t * 4 + k] = co;
    }
  }
}

// ---- kB: fused {k3b merge -> topidx in LDS} + {k4a lift, 8 tiles}. ----
// One block per batch (32 blocks, 256 thr). LDS overlay: merge K/I ->
// lift sd/sW after the merge result is parked in tidx[].
__global__ __launch_bounds__(256) void kB_merge_lift(
    const unsigned long long* __restrict__ candK, const int* __restrict__ candI,
    const float* __restrict__ x, const float* __restrict__ sal,
    const float* __restrict__ csal,
    const float* __restrict__ lift_W, const float* __restrict__ lift_b,
    const float* __restrict__ mu, const float* __restrict__ sigma,
    float* __restrict__ cloud)
{
  __shared__ __align__(16) char pool[49152];   // merge K/I <-> lift sd/sW
  __shared__ int tidx[KEFF];
  __shared__ float snf[32];
  int b = blockIdx.x, t = threadIdx.x;

  { // ---------------- phase 1: merge 8 sorted top-256 lists -------------
    unsigned long long* K = (unsigned long long*)pool;   // [2048] 16 KB
    int* I = (int*)(pool + 16384);                       // [2048]  8 KB
    for (int i = t; i < 2048; i += 256) {
      int r = i >> 9, o = i & 511;
      int lst = (o < 256) ? 2 * r : 2 * r + 1;
      int pos = (o < 256) ? o : 511 - o;
      K[i] = candK[(b * 8 + lst) * 256 + pos];
      I[i] = candI[(b * 8 + lst) * 256 + pos];
    }
    __syncthreads();

    #define CMPSWAP(i, l) { \
      unsigned long long a = K[i], cc = K[l]; \
      int ai = I[i], ci = I[l]; \
      bool prec = (a > cc) || (a == cc && ai < ci); \
      if (!prec) { K[i] = cc; K[l] = a; I[i] = ci; I[l] = ai; } }

    for (int j = 256; j > 0; j >>= 1) {
      for (int i = t; i < 2048; i += 256) {
        int l = i ^ j;
        if (l > i) CMPSWAP(i, l);
      }
      __syncthreads();
    }
    for (int i = t; i < 512; i += 256) {
      int pr = i >> 8, o = i & 255;
      int dst = pr * 1024 + 256 + o, src = pr * 1024 + 512 + 255 - o;
      K[dst] = K[src]; I[dst] = I[src];
    }
    __syncthreads();
    for (int j = 256; j > 0; j >>= 1) {
      for (int ii = t; ii < 1024; ii += 256) {
        int i = (ii < 512) ? ii : (ii + 512);
        int l = i ^ j;
        if (l > i) CMPSWAP(i, l);
      }
      __syncthreads();
    }
    for (int i = t; i < 256; i += 256) {
      K[256 + i] = K[1024 + 255 - i]; I[256 + i] = I[1024 + 255 - i];
    }
    __syncthreads();
    for (int j = 256; j > 0; j >>= 1) {
      for (int i = t; i < 512; i += 256) {
        int l = i ^ j;
        if (l > i) CMPSWAP(i, l);
      }
      __syncthreads();
    }
    #undef CMPSWAP
    if (t < 256) tidx[t] = I[t];
    __syncthreads();                     // park result before overlaying K/I
  }

  // ---------------- phase 2: dense->normalize->lift, 8 tiles of 32 ------
  float (*sd)[ADIM] = (float(*)[ADIM])pool;      // 16 KB (overlays K)
  float* sW = (float*)(pool + 16384);            // 32 KB (overlays I + rest)
  for (int e = t; e < ADIM * KDIM; e += 256) sW[e] = lift_W[e];
  int wv = t >> 6, lane = t & 63;

  for (int tile = 0; tile < 8; ++tile) {
    int p0 = tile * 32;
    __syncthreads();                             // sd reuse across tiles

    for (int e = t; e < 32 * ADIM; e += 256) {
      int p = e >> 7, a = e & 127;
      int n = tidx[p0 + p];
      int base = b * N_ + n;
      float v;
      if (a < IN_DIM)          v = x[(size_t)base * IN_DIM + a];
      else if (a == IN_DIM)    v = sal[base];
      else if (a == IN_DIM+1)  v = (float)n / (float)(N_ - 1);
      else                     v = csal[base];
      sd[p][a] = v;
    }
    __syncthreads();

    { // norms: 8 lanes per point
      int p = t >> 3, l8 = t & 7;
      float ss = 0.f;
      for (int a = l8; a < ADIM; a += 8) { float v = sd[p][a]; ss = fmaf(v, v, ss); }
      ss += __shfl_down(ss, 4);
      ss += __shfl_down(ss, 2);
      ss += __shfl_down(ss, 1);
      if (l8 == 0) snf[p] = 1.f / (sqrtf(ss) + EPS_);
    }
    __syncthreads();

    for (int e = t; e < 32 * ADIM; e += 256) {
      int p = e >> 7, a = e & 127;
      sd[p][a] = (sd[p][a] * snf[p] - mu[a]) / sigma[a];
    }
    __syncthreads();

    // lift: wave wv owns 8 points; lane = output dim k
    float acc[8];
    float lb = lift_b[lane];
    #pragma unroll
    for (int q = 0; q < 8; ++q) acc[q] = lb;
    #pragma unroll 1
    for (int a = 0; a < ADIM; a += 4) {
      float wl0 = sW[a*KDIM+lane],     wl1 = sW[(a+1)*KDIM+lane];
      float wl2 = sW[(a+2)*KDIM+lane], wl3 = sW[(a+3)*KDIM+lane];
      #pragma unroll
      for (int q = 0; q < 8; ++q) {
        int p = wv * 8 + q;
        acc[q] = fmaf(sd[p][a],   wl0, acc[q]);
        acc[q] = fmaf(sd[p][a+1], wl1, acc[q]);
        acc[q] = fmaf(sd[p][a+2], wl2, acc[q]);
        acc[q] = fmaf(sd[p][a+3], wl3, acc[q]);
      }
    }
    #pragma unroll
    for (int q = 0; q < 8; ++q) {
      int gp = b * KEFF + p0 + wv * 8 + q;
      cloud[(size_t)gp * KDIM + lane] = acc[q];  // coalesced 64 dwords
    }
  }
}

// ---- k4b: proj GEMM. Block = 32 points x 256 cols; 1024 blocks. ----
__global__ __launch_bounds__(256) void k4b_proj(
    const float* __restrict__ cloud, const float* __restrict__ proj_W,
    const float* __restrict__ proj_b, float* __restrict__ tokens)
{
  __shared__ float sc[32][KDIM];      // 8KB
  int t = threadIdx.x;
  int pg = blockIdx.x >> 2, cg = blockIdx.x & 3;

  { // load cloud tile: 2048 floats = 512 float4
    const float4* src = (const float4*)(cloud + (size_t)pg * 32 * KDIM);
    float4* dst = (float4*)sc;
    dst[t] = src[t];
    dst[t + 256] = src[t + 256];
  }
  __syncthreads();

  int col = cg * 256 + t;
  float acc[32];
  #pragma unroll
  for (int p = 0; p < 32; ++p) acc[p] = 0.f;

  float4 wcur;
  wcur.x = proj_W[0*DMODEL + col]; wcur.y = proj_W[1*DMODEL + col];
  wcur.z = proj_W[2*DMODEL + col]; wcur.w = proj_W[3*DMODEL + col];
  #pragma unroll 1
  for (int c = 0; c < KDIM; c += 4) {
    float4 wnext = {0.f, 0.f, 0.f, 0.f};
    if (c + 4 < KDIM) {
      wnext.x = proj_W[(size_t)(c+4)*DMODEL + col];
      wnext.y = proj_W[(size_t)(c+5)*DMODEL + col];
      wnext.z = proj_W[(size_t)(c+6)*DMODEL + col];
      wnext.w = proj_W[(size_t)(c+7)*DMODEL + col];
    }
    #pragma unroll
    for (int p = 0; p < 32; ++p) {
      float4 cv = *(const float4*)&sc[p][c];     // broadcast b128
      acc[p] = fmaf(cv.x, wcur.x, acc[p]);
      acc[p] = fmaf(cv.y, wcur.y, acc[p]);
      acc[p] = fmaf(cv.z, wcur.z, acc[p]);
      acc[p] = fmaf(cv.w, wcur.w, acc[p]);
    }
    wcur = wnext;
  }

  float pb = proj_b[col];
  int gp0 = pg * 32;
  #pragma unroll
  for (int p = 0; p < 32; ++p)
    tokens[(size_t)(gp0 + p) * DMODEL + col] = acc[p] + pb;
}

extern "C" void kernel_launch(void* const* d_in, const int* in_sizes, int n_in,
                              void* d_out, int out_size, void* d_ws, size_t ws_size,
                              hipStream_t stream)
{
  const float* x      = (const float*)d_in[0];
  const float* W1     = (const float*)d_in[1];
  const float* b1     = (const float*)d_in[2];
  const float* W2     = (const float*)d_in[3];
  const float* b2     = (const float*)d_in[4];
  const float* lift_W = (const float*)d_in[5];
  const float* lift_b = (const float*)d_in[6];
  const float* mu     = (const float*)d_in[7];
  const float* sigma  = (const float*)d_in[8];
  const float* proj_W = (const float*)d_in[9];
  const float* proj_b = (const float*)d_in[10];

  float* tokens = (float*)d_out;                        // [B,256,1024]
  float* ystarF = tokens + (size_t)B_ * KEFF * DMODEL;  // [B,N]

  // workspace layout (3.75 MB):
  //   [0, 1MB):   salD (dead after kA)          -- cloud[0..1MB) overlays
  //   [1, 2MB):   (free)                        -- cloud[1..2MB)
  //   [2, 2.5MB): salF   [2.5, 3MB): csalF
  //   [3, 3.5MB): candK  [3.5, 3.75MB): candI   (outside cloud: kB blocks
  //               read candK/I while other kB blocks write cloud)
  char* wsb = (char*)d_ws;
  double* salD   = (double*)wsb;                                   // B*N f64
  float*  cloud  = (float*)wsb;                                    // 2 MB
  float*  salF   = (float*)(wsb + (2<<20));
  float*  csalF  = salF + (size_t)B_ * N_;
  unsigned long long* candK = (unsigned long long*)(wsb + (3<<20));
  int*    candI  = (int*)(wsb + (3<<20) + (512<<10));

  k1_saliency<<<(B_ * N_) / K1_PTS, 512, 0, stream>>>(
      x, W1, b1, W2, b2, salD, salF);
  kA_softmax_sort<<<256 + B_, 256, 0, stream>>>(
      salD, salF, ystarF, csalF, candK, candI);
  kB_merge_lift<<<B_, 256, 0, stream>>>(
      candK, candI, x, salF, csalF, lift_W, lift_b, mu, sigma, cloud);
  k4b_proj<<<(B_ * KEFF / 32) * (DMODEL / 256), 256, 0, stream>>>(
      cloud, proj_W, proj_b, tokens);
}

// Round 5
// 252.859 us; speedup vs baseline: 1.4849x; 1.4849x over previous
//
#include <hip/hip_runtime.h>
#include <cmath>

#define B_ 32
#define N_ 4096
#define IN_DIM 125
#define ADIM 128
#define KDIM 64
#define DMODEL 1024
#define HID 64
#define KEFF 256
#define EPS_ 1e-6f

// ---------- k1: saliency MLP in fp64 (r1 structure, f32 weights inline) ----
// r0-r3 verdict: s_load W path pins VALU ~52% regardless of occupancy;
// LDS-broadcast W and VMEM W are worse. Keep the empirical winner.
// cvt_f64_f32 is exact -> bit-identical salD.
#define K1_PTS 128
__global__ __launch_bounds__(512) void k1_saliency(
    const float* __restrict__ x, const float* __restrict__ W1,
    const float* __restrict__ b1, const float* __restrict__ W2,
    const float* __restrict__ b2, double* __restrict__ salD,
    float* __restrict__ salF)
{
  __shared__ double smem[8000];              // 64000 B (xs + red overlay)
  float* xs = (float*)smem;                  // [128][125]
  int tid = threadIdx.x;
  int p0 = blockIdx.x * K1_PTS;

  { // stage x tile: 16000 floats = 4000 float4
    const float4* src = (const float4*)(x + (size_t)p0 * IN_DIM);
    float4* dst = (float4*)xs;
    for (int e = tid; e < (K1_PTS * IN_DIM) / 4; e += 512) dst[e] = src[e];
  }
  __syncthreads();

  int wv = __builtin_amdgcn_readfirstlane(tid >> 6);
  int lane = tid & 63;
  int jb = wv * 8;

  double acc0[8], acc1[8];
  #pragma unroll
  for (int jj = 0; jj < 8; ++jj) {
    double bv = (double)b1[jb + jj];
    acc0[jj] = bv; acc1[jj] = bv;
  }

  const float* xr0 = xs + lane * IN_DIM;          // stride 125 dw: 2-way free
  const float* xr1 = xs + (64 + lane) * IN_DIM;
  float wA[8], wB[8];
  #pragma unroll
  for (int jj = 0; jj < 8; ++jj) wA[jj] = W1[jb + jj];     // row 0
  float xv0 = xr0[0];
  float yv0 = xr1[0];

  #pragma unroll 1
  for (int d = 0; d < 124; d += 2) {
    float xv1 = xr0[d + 1];
    float yv1 = xr1[d + 1];
    #pragma unroll
    for (int jj = 0; jj < 8; ++jj) wB[jj] = W1[(d + 1) * HID + jb + jj];
    double xd0 = (double)xv0, yd0 = (double)yv0;
    #pragma unroll
    for (int jj = 0; jj < 8; ++jj) acc0[jj] = fma(xd0, (double)wA[jj], acc0[jj]);
    #pragma unroll
    for (int jj = 0; jj < 8; ++jj) acc1[jj] = fma(yd0, (double)wA[jj], acc1[jj]);
    xv0 = xr0[d + 2];
    yv0 = xr1[d + 2];
    #pragma unroll
    for (int jj = 0; jj < 8; ++jj) wA[jj] = W1[(d + 2) * HID + jb + jj];
    double xd1 = (double)xv1, yd1 = (double)yv1;
    #pragma unroll
    for (int jj = 0; jj < 8; ++jj) acc0[jj] = fma(xd1, (double)wB[jj], acc0[jj]);
    #pragma unroll
    for (int jj = 0; jj < 8; ++jj) acc1[jj] = fma(yd1, (double)wB[jj], acc1[jj]);
  }
  { // d = 124 (wA holds row 124)
    double xd = (double)xv0, yd = (double)yv0;
    #pragma unroll
    for (int jj = 0; jj < 8; ++jj) {
      acc0[jj] = fma(xd, (double)wA[jj], acc0[jj]);
      acc1[jj] = fma(yd, (double)wA[jj], acc1[jj]);
    }
  }

  double part0 = 0.0, part1 = 0.0;
  #pragma unroll
  for (int jj = 0; jj < 8; ++jj) {
    double w2 = (double)W2[jb + jj];
    part0 = fma(fmax(acc0[jj], 0.0), w2, part0);
    part1 = fma(fmax(acc1[jj], 0.0), w2, part1);
  }
  __syncthreads();                           // xs reads done
  double* red = smem;                        // [8][128] overlay (8 KB)
  red[wv * K1_PTS + lane] = part0;
  red[wv * K1_PTS + 64 + lane] = part1;
  __syncthreads();
  if (tid < K1_PTS) {
    double s = (double)b2[0];
    #pragma unroll
    for (int w = 0; w < 8; ++w) s += red[w * K1_PTS + tid];
    double sg = 1.0 / (1.0 + exp(-s));
    salD[p0 + tid] = sg;                     // f64 sort key (monotone == y*)
    salF[p0 + tid] = (float)sg;
  }
}

// ---- kA: fused {k3a chunk-sort (blocks 0..255)} + {k2 softmax/cumsum
//      (blocks 256..287)}. Both depend only on k1; one launch. ----
__global__ __launch_bounds__(256) void kA_softmax_sort(
    const double* __restrict__ salD, const float* __restrict__ salF,
    float* __restrict__ ystar, float* __restrict__ csal,
    unsigned long long* __restrict__ candK, int* __restrict__ candI)
{
  __shared__ unsigned long long K[512];
  __shared__ int I[512];
  __shared__ float wmax[4], wsum[4], wtot[4];
  int t = threadIdx.x;

  if (blockIdx.x < 256) {
    // ---------------- k3a: sort 512-chunk desc, keep top-256 ------------
    int bid = blockIdx.x;
    int b = bid >> 3, c = bid & 7;
    const double* y = salD + (size_t)b * N_ + c * 512;
    for (int i = t; i < 512; i += 256) {
      K[i] = __double_as_longlong(y[i]);    // y in (0,1): bits monotone
      I[i] = c * 512 + i;
    }
    __syncthreads();
    for (int k = 2; k <= 512; k <<= 1) {
      for (int j = k >> 1; j > 0; j >>= 1) {
        for (int i = t; i < 512; i += 256) {
          int l = i ^ j;
          if (l > i) {
            unsigned long long a = K[i], cc = K[l];
            int ai = I[i], ci = I[l];
            bool prec = (a > cc) || (a == cc && ai < ci);
            bool up = ((i & k) == 0);
            if (up ? !prec : prec) { K[i] = cc; K[l] = a; I[i] = ci; I[l] = ai; }
          }
        }
        __syncthreads();
      }
    }
    if (t < 256) {
      candK[(b * 8 + c) * 256 + t] = K[t];
      candI[(b * 8 + c) * 256 + t] = I[t];
    }
  } else {
    // ---------------- k2: softmax(sal/0.5) + cumsum(sal)/N --------------
    int b = blockIdx.x - 256;
    int lane = t & 63, wv = t >> 6;
    const float4* s4 = (const float4*)(salF + (size_t)b * N_);
    float v[16];
    #pragma unroll
    for (int k = 0; k < 4; ++k) {
      float4 a = s4[t * 4 + k];
      v[4*k] = a.x; v[4*k+1] = a.y; v[4*k+2] = a.z; v[4*k+3] = a.w;
    }
    float m = v[0];
    #pragma unroll
    for (int i = 1; i < 16; ++i) m = fmaxf(m, v[i]);
    #pragma unroll
    for (int off = 32; off > 0; off >>= 1) m = fmaxf(m, __shfl_down(m, off));
    if (lane == 0) wmax[wv] = m;
    __syncthreads();
    float M = fmaxf(fmaxf(wmax[0], wmax[1]), fmaxf(wmax[2], wmax[3]));

    float e[16];
    float se = 0.f;
    #pragma unroll
    for (int i = 0; i < 16; ++i) { e[i] = expf((v[i] - M) * 2.0f); se += e[i]; }
    float ss = se;
    #pragma unroll
    for (int off = 32; off > 0; off >>= 1) ss += __shfl_down(ss, off);
    if (lane == 0) wsum[wv] = ss;
    __syncthreads();
    float denom = (wsum[0] + wsum[1]) + (wsum[2] + wsum[3]);
    float rdenom = 1.f / denom;

    float p[16];
    p[0] = v[0];
    #pragma unroll
    for (int i = 1; i < 16; ++i) p[i] = p[i-1] + v[i];
    float T = p[15];
    float incl = T;
    #pragma unroll
    for (int off = 1; off < 64; off <<= 1) {
      float nv = __shfl_up(incl, off);
      if (lane >= off) incl += nv;
    }
    float wexcl = incl - T;
    if (lane == 63) wtot[wv] = incl;
    __syncthreads();
    float woff = 0.f;
    for (int w = 0; w < 4; ++w) if (w < wv) woff += wtot[w];
    float base = woff + wexcl;

    float4* y4 = (float4*)(ystar + (size_t)b * N_);
    float4* c4 = (float4*)(csal + (size_t)b * N_);
    const float invN = 1.f / (float)N_;
    #pragma unroll
    for (int k = 0; k < 4; ++k) {
      float4 yo, co;
      yo.x = e[4*k]   * rdenom; co.x = (base + p[4*k])   * invN;
      yo.y = e[4*k+1] * rdenom; co.y = (base + p[4*k+1]) * invN;
      yo.z = e[4*k+2] * rdenom; co.z = (base + p[4*k+2]) * invN;
      yo.w = e[4*k+3] * rdenom; co.w = (base + p[4*k+3]) * invN;
      y4[t * 4 + k] = yo;
      c4[t * 4 + k] = co;
    }
  }
}

// ---- k3b: merge-path top-256 of 8 sorted lists. r4 showed the bitonic
// merge is latency-bound (~30 barrier rounds at 1 block/CU). Merge-path:
// each element's output rank = own_pos + binary-search rank in partner
// list; 3 levels (8->4->2->1), ONE barrier per level, same comparator
// (K desc, I asc) -> identical sorted top-256. ----
__global__ __launch_bounds__(256) void k3b_merge(
    const unsigned long long* __restrict__ candK, const int* __restrict__ candI,
    int* __restrict__ topidx)
{
  __shared__ unsigned long long KA[2048];   // 16 KB
  __shared__ int IA[2048];                  //  8 KB
  __shared__ unsigned long long KB[1024];   //  8 KB
  __shared__ int IB[1024];                  //  4 KB
  int b = blockIdx.x, t = threadIdx.x;

  for (int i = t; i < 2048; i += 256) {
    KA[i] = candK[b * 2048 + i];
    IA[i] = candI[b * 2048 + i];
  }
  __syncthreads();

  // Level 1: 4 pairs of 256-lists in KA -> 4 top-256 lists in KB
  for (int e = t; e < 2048; e += 256) {
    int pr = e >> 9, q = e & 511;
    int own = q >> 8, pos = q & 255;
    int offSelf  = pr * 512 + own * 256;
    int offOther = pr * 512 + (own ^ 1) * 256;
    unsigned long long k = KA[offSelf + pos]; int idx = IA[offSelf + pos];
    int lo = 0, hi = 256;
    while (lo < hi) {
      int mid = (lo + hi) >> 1;
      unsigned long long ko = KA[offOther + mid]; int io = IA[offOther + mid];
      bool prec = (ko > k) || (ko == k && io < idx);
      if (prec) lo = mid + 1; else hi = mid;
    }
    int rank = pos + lo;
    if (rank < 256) { KB[pr * 256 + rank] = k; IB[pr * 256 + rank] = idx; }
  }
  __syncthreads();

  // Level 2: 2 pairs in KB -> 2 lists in KA[0..511]
  for (int e = t; e < 1024; e += 256) {
    int pr = e >> 9, q = e & 511;
    int own = q >> 8, pos = q & 255;
    int offSelf  = pr * 512 + own * 256;
    int offOther = pr * 512 + (own ^ 1) * 256;
    unsigned long long k = KB[offSelf + pos]; int idx = IB[offSelf + pos];
    int lo = 0, hi = 256;
    while (lo < hi) {
      int mid = (lo + hi) >> 1;
      unsigned long long ko = KB[offOther + mid]; int io = IB[offOther + mid];
      bool prec = (ko > k) || (ko == k && io < idx);
      if (prec) lo = mid + 1; else hi = mid;
    }
    int rank = pos + lo;
    if (rank < 256) { KA[pr * 256 + rank] = k; IA[pr * 256 + rank] = idx; }
  }
  __syncthreads();

  // Level 3: final pair KA[0..255] x KA[256..511] -> topidx (global)
  for (int e = t; e < 512; e += 256) {
    int own = e >> 8, pos = e & 255;
    int offSelf = own * 256, offOther = (own ^ 1) * 256;
    unsigned long long k = KA[offSelf + pos]; int idx = IA[offSelf + pos];
    int lo = 0, hi = 256;
    while (lo < hi) {
      int mid = (lo + hi) >> 1;
      unsigned long long ko = KA[offOther + mid]; int io = IA[offOther + mid];
      bool prec = (ko > k) || (ko == k && io < idx);
      if (prec) lo = mid + 1; else hi = mid;
    }
    int rank = pos + lo;
    if (rank < 256) topidx[b * KEFF + rank] = idx;
  }
}

// ---- k4a: gather top-32/block, dense->normalize->lift -> cloud[8192][64] ----
__global__ __launch_bounds__(256) void k4a_lift(
    const float* __restrict__ x, const float* __restrict__ sal,
    const float* __restrict__ csal, const int* __restrict__ topidx,
    const float* __restrict__ lift_W, const float* __restrict__ lift_b,
    const float* __restrict__ mu, const float* __restrict__ sigma,
    float* __restrict__ cloud)
{
  __shared__ float sd[32][ADIM];      // 16KB
  __shared__ float sW[ADIM * KDIM];   // 32KB
  __shared__ float snf[32];
  __shared__ int sidx[32];

  int t = threadIdx.x, bid = blockIdx.x;
  int b = bid >> 3, p0 = (bid & 7) * 32;

  if (t < 32) sidx[t] = topidx[b * KEFF + p0 + t];
  for (int e = t; e < ADIM * KDIM; e += 256) sW[e] = lift_W[e];
  __syncthreads();

  for (int e = t; e < 32 * ADIM; e += 256) {
    int p = e >> 7, a = e & 127;
    int n = sidx[p];
    int base = b * N_ + n;
    float v;
    if (a < IN_DIM)          v = x[(size_t)base * IN_DIM + a];
    else if (a == IN_DIM)    v = sal[base];
    else if (a == IN_DIM+1)  v = (float)n / (float)(N_ - 1);
    else                     v = csal[base];
    sd[p][a] = v;
  }
  __syncthreads();

  { // norms: 8 lanes per point
    int p = t >> 3, l8 = t & 7;
    float ss = 0.f;
    for (int a = l8; a < ADIM; a += 8) { float v = sd[p][a]; ss = fmaf(v, v, ss); }
    ss += __shfl_down(ss, 4);
    ss += __shfl_down(ss, 2);
    ss += __shfl_down(ss, 1);
    if (l8 == 0) snf[p] = 1.f / (sqrtf(ss) + EPS_);
  }
  __syncthreads();

  for (int e = t; e < 32 * ADIM; e += 256) {
    int p = e >> 7, a = e & 127;
    sd[p][a] = (sd[p][a] * snf[p] - mu[a]) / sigma[a];
  }
  __syncthreads();

  // lift: wave wv owns 8 points; lane = output dim k
  int wv = t >> 6, lane = t & 63;
  float acc[8];
  float lb = lift_b[lane];
  #pragma unroll
  for (int q = 0; q < 8; ++q) acc[q] = lb;
  #pragma unroll 1
  for (int a = 0; a < ADIM; a += 4) {
    float wl0 = sW[a*KDIM+lane],     wl1 = sW[(a+1)*KDIM+lane];
    float wl2 = sW[(a+2)*KDIM+lane], wl3 = sW[(a+3)*KDIM+lane];
    #pragma unroll
    for (int q = 0; q < 8; ++q) {
      int p = wv * 8 + q;
      acc[q] = fmaf(sd[p][a],   wl0, acc[q]);
      acc[q] = fmaf(sd[p][a+1], wl1, acc[q]);
      acc[q] = fmaf(sd[p][a+2], wl2, acc[q]);
      acc[q] = fmaf(sd[p][a+3], wl3, acc[q]);
    }
  }
  #pragma unroll
  for (int q = 0; q < 8; ++q) {
    int gp = b * KEFF + p0 + wv * 8 + q;
    cloud[(size_t)gp * KDIM + lane] = acc[q];    // coalesced 64 dwords
  }
}

// ---- k4b: proj GEMM. Block = 32 points x 256 cols; 1024 blocks. ----
__global__ __launch_bounds__(256) void k4b_proj(
    const float* __restrict__ cloud, const float* __restrict__ proj_W,
    const float* __restrict__ proj_b, float* __restrict__ tokens)
{
  __shared__ float sc[32][KDIM];      // 8KB
  int t = threadIdx.x;
  int pg = blockIdx.x >> 2, cg = blockIdx.x & 3;

  { // load cloud tile: 2048 floats = 512 float4
    const float4* src = (const float4*)(cloud + (size_t)pg * 32 * KDIM);
    float4* dst = (float4*)sc;
    dst[t] = src[t];
    dst[t + 256] = src[t + 256];
  }
  __syncthreads();

  int col = cg * 256 + t;
  float acc[32];
  #pragma unroll
  for (int p = 0; p < 32; ++p) acc[p] = 0.f;

  float4 wcur;
  wcur.x = proj_W[0*DMODEL + col]; wcur.y = proj_W[1*DMODEL + col];
  wcur.z = proj_W[2*DMODEL + col]; wcur.w = proj_W[3*DMODEL + col];
  #pragma unroll 1
  for (int c = 0; c < KDIM; c += 4) {
    float4 wnext = {0.f, 0.f, 0.f, 0.f};
    if (c + 4 < KDIM) {
      wnext.x = proj_W[(size_t)(c+4)*DMODEL + col];
      wnext.y = proj_W[(size_t)(c+5)*DMODEL + col];
      wnext.z = proj_W[(size_t)(c+6)*DMODEL + col];
      wnext.w = proj_W[(size_t)(c+7)*DMODEL + col];
    }
    #pragma unroll
    for (int p = 0; p < 32; ++p) {
      float4 cv = *(const float4*)&sc[p][c];     // broadcast b128
      acc[p] = fmaf(cv.x, wcur.x, acc[p]);
      acc[p] = fmaf(cv.y, wcur.y, acc[p]);
      acc[p] = fmaf(cv.z, wcur.z, acc[p]);
      acc[p] = fmaf(cv.w, wcur.w, acc[p]);
    }
    wcur = wnext;
  }

  float pb = proj_b[col];
  int gp0 = pg * 32;
  #pragma unroll
  for (int p = 0; p < 32; ++p)
    tokens[(size_t)(gp0 + p) * DMODEL + col] = acc[p] + pb;
}

extern "C" void kernel_launch(void* const* d_in, const int* in_sizes, int n_in,
                              void* d_out, int out_size, void* d_ws, size_t ws_size,
                              hipStream_t stream)
{
  const float* x      = (const float*)d_in[0];
  const float* W1     = (const float*)d_in[1];
  const float* b1     = (const float*)d_in[2];
  const float* W2     = (const float*)d_in[3];
  const float* b2     = (const float*)d_in[4];
  const float* lift_W = (const float*)d_in[5];
  const float* lift_b = (const float*)d_in[6];
  const float* mu     = (const float*)d_in[7];
  const float* sigma  = (const float*)d_in[8];
  const float* proj_W = (const float*)d_in[9];
  const float* proj_b = (const float*)d_in[10];

  float* tokens = (float*)d_out;                        // [B,256,1024]
  float* ystarF = tokens + (size_t)B_ * KEFF * DMODEL;  // [B,N]

  // workspace layout (3.1 MB):
  //   [0, 2MB):  salD(1MB) | candK(512K) | candI(256K) -- dead after k3b;
  //              cloud(2MB) overlays (written by k4a, after k3b completes)
  //   [2, 2.5MB): salF   [2.5, 3MB): csalF   [3MB, +32K): topidx
  char* wsb = (char*)d_ws;
  double* salD   = (double*)wsb;                                   // B*N f64
  unsigned long long* candK = (unsigned long long*)(wsb + (1<<20));
  int*    candI  = (int*)(wsb + (1<<20) + (512<<10));
  float*  cloud  = (float*)wsb;                                    // overlay
  float*  salF   = (float*)(wsb + (2<<20));
  float*  csalF  = salF + (size_t)B_ * N_;
  int*    topidx = (int*)(wsb + (3<<20));

  k1_saliency<<<(B_ * N_) / K1_PTS, 512, 0, stream>>>(
      x, W1, b1, W2, b2, salD, salF);
  kA_softmax_sort<<<256 + B_, 256, 0, stream>>>(
      salD, salF, ystarF, csalF, candK, candI);
  k3b_merge<<<B_, 256, 0, stream>>>(candK, candI, topidx);
  k4a_lift<<<B_ * 8, 256, 0, stream>>>(
      x, salF, csalF, topidx, lift_W, lift_b, mu, sigma, cloud);
  k4b_proj<<<(B_ * KEFF / 32) * (DMODEL / 256), 256, 0, stream>>>(
      cloud, proj_W, proj_b, tokens);
}